// Round 9
// baseline (473.027 us; speedup 1.0000x reference)
//
#include <hip/hip_runtime.h>

// ---------------------------------------------------------------------------
// RVMixtureSynthesizers: q = query@Wq^T + bq ; k = key@Wk^T + bk
//   energy = q@k^T + attn_bias ; attention = softmax(energy) ; out = attention@value
// Outputs: out [16,1024,1024] fp32, attention [16,1024,1024] fp32 (concat in d_out)
//
// R8: all GEMMs unified into a faithful m201-style 8-phase kernel.
// Split-bf16 GEMM expressed as K=3072 with per-region pointers A={qh,qh,ql},
// B={kh,kl,kh} (hh+hl+lh). 256x256 tile, BK=64, 8 waves, 128KB LDS.
// Per K-tile 4 phases (C-quadrants), 1 cold vmcnt(4) gate at q3, barrier/phase.
// Swizzle chunk^=(row&7) both sides (R1-verified family).
// ---------------------------------------------------------------------------

#define AS1 __attribute__((address_space(1)))
#define AS3 __attribute__((address_space(3)))
#define VMCNT(n) asm volatile("s_waitcnt vmcnt(" #n ")" ::: "memory")
#define LGKM(n)  asm volatile("s_waitcnt lgkmcnt(" #n ")" ::: "memory")
#define SBARRIER asm volatile("s_barrier" ::: "memory")
#define SB0 __builtin_amdgcn_sched_barrier(0)

typedef __bf16 bf16;
typedef __bf16 bf16x4 __attribute__((ext_vector_type(4)));
typedef __bf16 bf16x8 __attribute__((ext_vector_type(8)));
typedef float  f32x4  __attribute__((ext_vector_type(4)));

constexpr int BATCH = 16;
constexpr int S = 1024;
constexpr int D = 1024;
constexpr long NBSD = (long)BATCH * S * D;   // 16777216

__device__ __forceinline__ void stage16(const bf16* src, const bf16* dst) {
  __builtin_amdgcn_global_load_lds((const AS1 void*)src, (AS3 void*)dst, 16, 0, 0);
}

// ---------------------------------------------------------------------------
__global__ __launch_bounds__(256) void split_convert(
    const float* __restrict__ in, bf16* __restrict__ hi, bf16* __restrict__ lo, int n4) {
  int i = blockIdx.x * blockDim.x + threadIdx.x;
  int stride = gridDim.x * blockDim.x;
  for (; i < n4; i += stride) {
    f32x4 x = ((const f32x4*)in)[i];
    bf16x4 h, l;
#pragma unroll
    for (int j = 0; j < 4; ++j) {
      float v = x[j];
      bf16 hh = (bf16)v;
      h[j] = hh;
      l[j] = (bf16)(v - (float)hh);
    }
    ((bf16x4*)hi)[i] = h;
    ((bf16x4*)lo)[i] = l;
  }
}

// ---------------------------------------------------------------------------
__global__ __launch_bounds__(256) void transpose_convert(
    const float* __restrict__ v, bf16* __restrict__ vT) {
  __shared__ float tile[32][33];
  const int b = blockIdx.z;
  const int t0 = blockIdx.y * 32, d0 = blockIdx.x * 32;
  const int tx = threadIdx.x & 31, ty = threadIdx.x >> 5;
  const float* src = v + (long)b * S * D;
#pragma unroll
  for (int i = 0; i < 4; ++i)
    tile[ty + i * 8][tx] = src[(long)(t0 + ty + i * 8) * D + d0 + tx];
  __syncthreads();
  bf16* dst = vT + (long)b * D * S;
#pragma unroll
  for (int i = 0; i < 4; ++i)
    dst[(long)(d0 + ty + i * 8) * S + t0 + tx] = (bf16)tile[tx][ty + i * 8];
}

// ---------------------------------------------------------------------------
// 8-phase GEMM (m201 geometry). C = sum over K-regions of A_r * B_r^T.
// 256x256 tile, BK=64, 512 thr (8 waves 2Mx4N; wave C = 128x64 = 8x4 frags of
// 16x16). LDS [2 buf][A/B][2 half][128x64] = 128 KB. Per K-tile 4 phases
// (C-quadrants q=(mh,nh)); each phase: ds_reads for its quadrant; stage one
// 16KB half-tile of a FUTURE tile; lgkm(0); 16 MFMA; barrier.
// Stage schedule: q0: A1(kt+1)  q1: B1(kt+1)  q2: B0(kt+2)  q3: A0(kt+2)+GATE.
// Gate vmcnt(4) at q3 retires ALL of tile kt+1 (cold: newest retired load is
// 2 phases old), leaving {B0,A0}(kt+2) in flight. Never drains mid-loop.
// EPI: 0=proj (col-bias, split bf16 out), 1=energy (+bias fp32), 2=plain fp32.
template <int EPI, int NREG>
__global__ __launch_bounds__(512, 1) void gemm_p4(
    const bf16* __restrict__ A0g, const bf16* __restrict__ A1g,
    const bf16* __restrict__ A2g, long a_bs,
    const bf16* __restrict__ B0g, const bf16* __restrict__ B1g,
    const bf16* __restrict__ B2g, long b_bs,
    const float* __restrict__ bias,
    bf16* __restrict__ Ch, bf16* __restrict__ Cl,
    float* __restrict__ Cf, long c_bs) {
  constexpr int NT = NREG * 16;              // K-tiles of 64
  __shared__ bf16 lds[2][2][2][8192];        // [buf][A/B][half][128*64]

  const int tid = threadIdx.x;
  const int lane = tid & 63, wid = tid >> 6;
  const int wr = wid >> 2, wc = wid & 3;     // 2x4 wave grid
  const int fr = lane & 15, fq = lane >> 4;

  // T1 bijective XCD swizzle (nwg=256)
  const int w = blockIdx.x;
  const int swz = (w & 7) * 32 + (w >> 3);
  int z, by, bx;
  if constexpr (EPI == 0) { z = 0; by = swz >> 2; bx = swz & 3; }
  else { z = swz >> 4; by = (swz >> 2) & 3; bx = swz & 3; }
  const long brow = (long)by * 256, bcol = (long)bx * 256;

  const bf16* A0 = A0g + (long)z * a_bs;
  const bf16* A1 = A1g + (long)z * a_bs;
  const bf16* A2 = A2g + (long)z * a_bs;
  const bf16* B0 = B0g + (long)z * b_bs;
  const bf16* B1 = B1g + (long)z * b_bs;
  const bf16* B2 = B2g + (long)z * b_bs;

  auto APTR = [&](int t) -> const bf16* {
    const int r = t >> 4; return r == 0 ? A0 : (r == 1 ? A1 : A2);
  };
  auto BPTR = [&](int t) -> const bf16* {
    const int r = t >> 4; return r == 0 ? B0 : (r == 1 ? B1 : B2);
  };

  // staging: thread -> (row 0..63, chunk 0..7 of 16B), swizzled source chunk
  const int srow64 = tid >> 3;
  const int scol = ((tid & 7) ^ (srow64 & 7)) * 8;

  // fragment read offsets (elems): row m*16+fr, chunk (kk*4+fq)^(fr&7)
  const int c0 = (((fq ^ (fr & 3)) | (((fr >> 2) & 1) << 2))) * 8;  // kk=0; kk=1 -> c0^32
  const int arow = fr * 64;
  const int brow_ = (wc & 1) * 4096 + fr * 64;

  f32x4 acc[8][4] = {};
  bf16x8 afr[4][2], bfr[4][2];

#define STG(ARR, H, T) do { \
    const bf16* _s = ((ARR) ? BPTR(T) : APTR(T)) + \
      (((ARR) ? bcol : brow) + (H) * 128 + srow64) * 1024 + ((T) & 15) * 64 + scol; \
    const bf16* _d = &lds[(T) & 1][ARR][H][wid * 512]; \
    stage16(_s, _d); stage16(_s + 65536, _d + 4096); \
  } while (0)

#define RD_A() { const bf16* p = &lds[kt & 1][0][wr][0]; \
    _Pragma("unroll") for (int m = 0; m < 4; ++m) { \
      afr[m][0] = *(const bf16x8*)&p[(MBASE + m) * 1024 + arow + c0]; \
      afr[m][1] = *(const bf16x8*)&p[(MBASE + m) * 1024 + arow + (c0 ^ 32)]; } }

#define RD_B(N0) { const bf16* p = &lds[kt & 1][1][wc >> 1][0]; \
    _Pragma("unroll") for (int n = 0; n < 2; ++n) { \
      bfr[N0 + n][0] = *(const bf16x8*)&p[(N0 + n) * 1024 + brow_ + c0]; \
      bfr[N0 + n][1] = *(const bf16x8*)&p[(N0 + n) * 1024 + brow_ + (c0 ^ 32)]; } }

#define MM(M0, N0) \
    __builtin_amdgcn_s_setprio(1); \
    _Pragma("unroll") for (int kk = 0; kk < 2; ++kk) \
      _Pragma("unroll") for (int m = 0; m < 4; ++m) \
        _Pragma("unroll") for (int n = 0; n < 2; ++n) \
          acc[M0 + m][N0 + n] = __builtin_amdgcn_mfma_f32_16x16x32_bf16( \
              afr[m][kk], bfr[N0 + n][kk], acc[M0 + m][N0 + n], 0, 0, 0); \
    __builtin_amdgcn_s_setprio(0)

  // ---- prologue: tile0 all 4 halves, then B0(1), A0(1) (12 loads, in order)
  STG(0, 0, 0); STG(0, 1, 0); STG(1, 0, 0); STG(1, 1, 0);
  STG(1, 0, 1); STG(0, 0, 1);
  VMCNT(4);          // tile0 retired; {B0(1),A0(1)} in flight (steady invariant)
  SBARRIER;

  for (int kt = 0; kt < NT; ++kt) {
    const bool p1 = kt + 1 < NT, p2 = kt + 2 < NT;
    // ---- q0: quadrant (mh0, n01): reads A m0-3 (8) + B n0-1 (4)
    { constexpr int MBASE = 0; RD_A(); }
    RD_B(0);
    if (p1) STG(0, 1, kt + 1);
    LGKM(0); SB0;
    MM(0, 0);
    SBARRIER;
    // ---- q1: (mh0, n23): reads B n2-3 (4)
    RD_B(2);
    if (p1) STG(1, 1, kt + 1);
    LGKM(0); SB0;
    MM(0, 2);
    SBARRIER;
    // ---- q2: (mh1, n01): reads A m4-7 (8)
    { constexpr int MBASE = 4; RD_A(); }
    if (p2) STG(1, 0, kt + 2);
    LGKM(0); SB0;
    MM(4, 0);
    SBARRIER;
    // ---- q3: (mh1, n23): no reads; stage + the one gate per K-tile
    if (p2) { STG(0, 0, kt + 2); VMCNT(4); }
    else if (p1) { VMCNT(0); }
    SB0;
    MM(4, 2);
    SBARRIER;
  }
#undef STG
#undef RD_A
#undef RD_B
#undef MM

  // Epilogue. 16x16 C/D frag [m89]: col = lane&15, row = (lane>>4)*4 + j
  if constexpr (EPI == 0) {
#pragma unroll
    for (int n = 0; n < 4; ++n) {
      const long col = bcol + wc * 64 + n * 16 + fr;
      const float bv = bias[col];
#pragma unroll
      for (int m = 0; m < 8; ++m) {
        const long row0 = brow + wr * 128 + m * 16 + fq * 4;
#pragma unroll
        for (int j = 0; j < 4; ++j) {
          const float c = acc[m][n][j] + bv;
          const bf16 h = (bf16)c;
          const bf16 l = (bf16)(c - (float)h);
          const long idx = (row0 + j) * 1024 + col;
          Ch[idx] = h;
          Cl[idx] = l;
        }
      }
    }
  } else if constexpr (EPI == 1) {
    float* Cz = Cf + (long)z * c_bs;
#pragma unroll
    for (int n = 0; n < 4; ++n) {
      const long col = bcol + wc * 64 + n * 16 + fr;
#pragma unroll
      for (int m = 0; m < 8; ++m) {
        const long row0 = brow + wr * 128 + m * 16 + fq * 4;
#pragma unroll
        for (int j = 0; j < 4; ++j) {
          const long row = row0 + j;
          Cz[row * 1024 + col] = acc[m][n][j] + bias[row * 1024 + col];
        }
      }
    }
  } else {
    float* Cz = Cf + (long)z * c_bs;
#pragma unroll
    for (int n = 0; n < 4; ++n) {
      const long col = bcol + wc * 64 + n * 16 + fr;
#pragma unroll
      for (int m = 0; m < 8; ++m) {
        const long row0 = brow + wr * 128 + m * 16 + fq * 4;
#pragma unroll
        for (int j = 0; j < 4; ++j)
          Cz[(row0 + j) * 1024 + col] = acc[m][n][j];
      }
    }
  }
}

// ---------------------------------------------------------------------------
__global__ __launch_bounds__(256) void softmax_rows(
    float* __restrict__ attn, bf16* __restrict__ attn_bf) {
  const long row = blockIdx.x;
  float* p = attn + row * 1024;
  const int tid = threadIdx.x, lane = tid & 63, wid = tid >> 6;

  f32x4 x = ((const f32x4*)p)[tid];
  float m = fmaxf(fmaxf(x[0], x[1]), fmaxf(x[2], x[3]));
#pragma unroll
  for (int off = 32; off; off >>= 1) m = fmaxf(m, __shfl_xor(m, off));
  __shared__ float redm[4];
  if (lane == 0) redm[wid] = m;
  __syncthreads();
  m = fmaxf(fmaxf(redm[0], redm[1]), fmaxf(redm[2], redm[3]));

  f32x4 e;
#pragma unroll
  for (int j = 0; j < 4; ++j) e[j] = __expf(x[j] - m);
  float s = e[0] + e[1] + e[2] + e[3];
#pragma unroll
  for (int off = 32; off; off >>= 1) s += __shfl_xor(s, off);
  __shared__ float reds[4];
  if (lane == 0) reds[wid] = s;
  __syncthreads();
  s = reds[0] + reds[1] + reds[2] + reds[3];

  const float inv = 1.0f / s;
  f32x4 r;
  bf16x4 rb;
#pragma unroll
  for (int j = 0; j < 4; ++j) {
    r[j] = e[j] * inv;
    rb[j] = (bf16)r[j];
  }
  ((f32x4*)p)[tid] = r;
  ((bf16x4*)(attn_bf + row * 1024))[tid] = rb;
}

// ---------------------------------------------------------------------------
extern "C" void kernel_launch(void* const* d_in, const int* in_sizes, int n_in,
                              void* d_out, int out_size, void* d_ws, size_t ws_size,
                              hipStream_t stream) {
  const float* query     = (const float*)d_in[0];
  const float* key       = (const float*)d_in[1];
  const float* value     = (const float*)d_in[2];
  const float* attn_bias = (const float*)d_in[3];
  const float* Wq        = (const float*)d_in[4];
  const float* bq        = (const float*)d_in[5];
  const float* Wk        = (const float*)d_in[6];
  const float* bk        = (const float*)d_in[7];

  float* out  = (float*)d_out;          // [16,1024,1024]
  float* attn = out + NBSD;             // [16,1024,1024]

  // ws carve (bf16 elements). Total = 6*NBSD + 4*D*D = 200 MiB.
  bf16* ws    = (bf16*)d_ws;
  bf16* q_hi  = ws;
  bf16* q_lo  = ws + NBSD;
  bf16* k_hi  = ws + 2 * NBSD;
  bf16* k_lo  = ws + 3 * NBSD;
  bf16* Wq_hi = ws + 4 * NBSD;
  bf16* Wq_lo = Wq_hi + (long)D * D;
  bf16* Wk_hi = Wq_lo + (long)D * D;
  bf16* Wk_lo = Wk_hi + (long)D * D;
  bf16* scr   = Wk_lo + (long)D * D;    // 2*NBSD scratch
  bf16* key_hi = scr;
  bf16* key_lo = scr + NBSD;
  bf16* valueT  = scr;                  // reused after key splits die
  bf16* attn_bf = scr + NBSD;
  bf16* query_hi = (bf16*)d_out;        // lives in `out` region until PV
  bf16* query_lo = query_hi + NBSD;

  // 1) split conversions
  split_convert<<<2048, 256, 0, stream>>>(query, query_hi, query_lo, (int)(NBSD / 4));
  split_convert<<<2048, 256, 0, stream>>>(key, key_hi, key_lo, (int)(NBSD / 4));
  split_convert<<<512, 256, 0, stream>>>(Wq, Wq_hi, Wq_lo, D * D / 4);
  split_convert<<<512, 256, 0, stream>>>(Wk, Wk_hi, Wk_lo, D * D / 4);

  // 2) projections: K-regions A={qh,qh,ql}, B={Wh,Wl,Wh} (hh+hl+lh)
  gemm_p4<0, 3><<<256, 512, 0, stream>>>(query_hi, query_hi, query_lo, 0,
                                         Wq_hi, Wq_lo, Wq_hi, 0,
                                         bq, q_hi, q_lo, nullptr, 0);
  gemm_p4<0, 3><<<256, 512, 0, stream>>>(key_hi, key_hi, key_lo, 0,
                                         Wk_hi, Wk_lo, Wk_hi, 0,
                                         bk, k_hi, k_lo, nullptr, 0);

  // 3) value transpose (key splits now dead)
  transpose_convert<<<dim3(32, 32, 16), 256, 0, stream>>>(value, valueT);

  // 4) energy = q k^T + bias (16 z x 4x4 = 256 blocks)
  gemm_p4<1, 3><<<256, 512, 0, stream>>>(q_hi, q_hi, q_lo, (long)S * D,
                                         k_hi, k_lo, k_hi, (long)S * D,
                                         attn_bias, nullptr, nullptr, attn, (long)S * S);

  // 5) softmax in place + bf16 copy
  softmax_rows<<<BATCH * S, 256, 0, stream>>>(attn, attn_bf);

  // 6) out = attention @ value (plain, K=1024)
  gemm_p4<2, 1><<<256, 512, 0, stream>>>(attn_bf, attn_bf, attn_bf, (long)S * S,
                                         valueT, valueT, valueT, (long)D * S,
                                         nullptr, nullptr, nullptr, out, (long)S * D);
}

// Round 10
// 467.273 us; speedup vs baseline: 1.0123x; 1.0123x over previous
//
#include <hip/hip_runtime.h>

// ---------------------------------------------------------------------------
// RVMixtureSynthesizers: q = query@Wq^T + bq ; k = key@Wk^T + bk
//   energy = q@k^T + attn_bias ; attention = softmax(energy) ; out = attention@value
// Outputs: out [16,1024,1024] fp32, attention [16,1024,1024] fp32 (concat in d_out)
//
// R9: algebraic restructure. q,k are never output, so:
//   energy = Q·(Wq^T Wk)·K^T + v1[s] + v2[t] + c + attn_bias
// with M = Wq^T Wk (tiny), v1 = Q·(Wq^T bk), v2 = K·(Wk^T bq), c = bq·bk.
// Replaces two 103-GF projection GEMMs with one 103-GF QM GEMM + ~2-GF fp32
// outer-product kernel (MT, split output) + fused rank-1 corrections.
// Big GEMMs are verbatim R5 structure (measured best: 107 us each).
// Split-bf16 (hh+hl+lh) for QM and energy; PV plain bf16.
// ---------------------------------------------------------------------------

#define AS1 __attribute__((address_space(1)))
#define AS3 __attribute__((address_space(3)))
#define VMCNT(n) asm volatile("s_waitcnt vmcnt(" #n ")" ::: "memory")
#define LGKM(n)  asm volatile("s_waitcnt lgkmcnt(" #n ")" ::: "memory")
#define SBARRIER asm volatile("s_barrier" ::: "memory")
#define SB0 __builtin_amdgcn_sched_barrier(0)

typedef __bf16 bf16;
typedef __bf16 bf16x4 __attribute__((ext_vector_type(4)));
typedef __bf16 bf16x8 __attribute__((ext_vector_type(8)));
typedef float  f32x4  __attribute__((ext_vector_type(4)));
typedef float  f32x16 __attribute__((ext_vector_type(16)));

constexpr int BATCH = 16;
constexpr int S = 1024;
constexpr int D = 1024;
constexpr long NBSD = (long)BATCH * S * D;   // 16777216

constexpr int GBM = 256, GBN = 256, GBK = 32;
constexpr int NTK = 1024 / GBK;              // 32 K-tiles
constexpr int ARR = GBM * GBK;               // 8192 elems = 16 KB per array

__device__ __forceinline__ void stage16(const bf16* src, const bf16* dst) {
  __builtin_amdgcn_global_load_lds((const AS1 void*)src, (AS3 void*)dst, 16, 0, 0);
}

// ---------------------------------------------------------------------------
// fp32 -> (hi,lo) bf16 split + fused dot with w (v[row] = row . w).
// One wave per row of 1024; grid 4096 x 256 (4 waves/block).
__global__ __launch_bounds__(256) void split_convert_dot(
    const float* __restrict__ in, bf16* __restrict__ hi, bf16* __restrict__ lo,
    const float* __restrict__ w, float* __restrict__ v) {
  const int wid = threadIdx.x >> 6, lane = threadIdx.x & 63;
  const long row = (long)blockIdx.x * 4 + wid;
  const f32x4* src = (const f32x4*)(in + row * 1024);
  const f32x4* w4 = (const f32x4*)w;
  float acc = 0.f;
#pragma unroll
  for (int it = 0; it < 4; ++it) {
    const int idx = it * 64 + lane;
    f32x4 x = src[idx];
    f32x4 wv = w4[idx];
    bf16x4 h, l;
#pragma unroll
    for (int j = 0; j < 4; ++j) {
      float vv = x[j];
      bf16 hh = (bf16)vv;
      h[j] = hh;
      l[j] = (bf16)(vv - (float)hh);
      acc += vv * wv[j];
    }
    *(bf16x4*)(hi + row * 1024 + idx * 4) = h;
    *(bf16x4*)(lo + row * 1024 + idx * 4) = l;
  }
#pragma unroll
  for (int off = 32; off; off >>= 1) acc += __shfl_xor(acc, off);
  if (lane == 0) v[row] = acc;
}

// ---------------------------------------------------------------------------
// Partial sums for w1[e] = sum_d Wq[d,e]*bk[d], w2[e] = sum_d Wk[d,e]*bq[d],
// plus c = bq.bk and the zeros vector. Deterministic (no atomics).
// Blocks 0..31: w1 partials (dc = b>>2, e-range (b&3)*256); 32..63: w2; 64: c+zeros.
__global__ __launch_bounds__(256) void wpart_kernel(
    const float* __restrict__ Wq, const float* __restrict__ Wk,
    const float* __restrict__ bq, const float* __restrict__ bk,
    float* __restrict__ w1p, float* __restrict__ w2p,
    float* __restrict__ cbuf, float* __restrict__ zeros) {
  const int b = blockIdx.x, t = threadIdx.x;
  if (b < 32) {
    const int dc = b >> 2, e = (b & 3) * 256 + t;
    float s = 0.f;
    for (int d = dc * 128; d < dc * 128 + 128; ++d) s += Wq[(long)d * 1024 + e] * bk[d];
    w1p[dc * 1024 + e] = s;
  } else if (b < 64) {
    const int dc = (b - 32) >> 2, e = ((b - 32) & 3) * 256 + t;
    float s = 0.f;
    for (int d = dc * 128; d < dc * 128 + 128; ++d) s += Wk[(long)d * 1024 + e] * bq[d];
    w2p[dc * 1024 + e] = s;
  } else {
    for (int i = t; i < 1024; i += 256) zeros[i] = 0.f;
    float s = 0.f;
    for (int i = t; i < 1024; i += 256) s += bq[i] * bk[i];
#pragma unroll
    for (int off = 32; off; off >>= 1) s += __shfl_xor(s, off);
    __shared__ float red[4];
    if ((t & 63) == 0) red[t >> 6] = s;
    __syncthreads();
    if (t == 0) cbuf[0] = red[0] + red[1] + red[2] + red[3];
  }
}

__global__ __launch_bounds__(256) void wreduce_kernel(
    const float* __restrict__ w1p, const float* __restrict__ w2p,
    float* __restrict__ w1, float* __restrict__ w2) {
  const int b = blockIdx.x, t = threadIdx.x;
  if (b < 4) {
    const int e = b * 256 + t;
    float s = 0.f;
#pragma unroll
    for (int dc = 0; dc < 8; ++dc) s += w1p[dc * 1024 + e];
    w1[e] = s;
  } else {
    const int e = (b - 4) * 256 + t;
    float s = 0.f;
#pragma unroll
    for (int dc = 0; dc < 8; ++dc) s += w2p[dc * 1024 + e];
    w2[e] = s;
  }
}

// ---------------------------------------------------------------------------
// MT[j,d] = sum_e Wk[e,j] * Wq[e,d]  (= (Wq^T Wk)^T), fp32 accumulate,
// split-bf16 output. 64x64 tile per block, grid 16x16, 256 thr (4x4/thread).
__global__ __launch_bounds__(256) void mt_split(
    const float* __restrict__ Wk, const float* __restrict__ Wq,
    bf16* __restrict__ MTh, bf16* __restrict__ MTl) {
  __shared__ float sK[64][64], sQ[64][64];
  const int t = threadIdx.x;
  const int j0 = blockIdx.y * 64, d0 = blockIdx.x * 64;
  const int tj = t >> 4, td = t & 15;
  float acc[4][4] = {};
  for (int e0 = 0; e0 < 1024; e0 += 64) {
    __syncthreads();
#pragma unroll
    for (int it = 0; it < 4; ++it) {
      const int r = (t >> 4) + it * 16, c4 = (t & 15) * 4;
      *(f32x4*)&sK[r][c4] = *(const f32x4*)&Wk[(long)(e0 + r) * 1024 + j0 + c4];
      *(f32x4*)&sQ[r][c4] = *(const f32x4*)&Wq[(long)(e0 + r) * 1024 + d0 + c4];
    }
    __syncthreads();
#pragma unroll 4
    for (int e = 0; e < 64; ++e) {
      f32x4 a = *(const f32x4*)&sK[e][tj * 4];
      f32x4 b = *(const f32x4*)&sQ[e][td * 4];
#pragma unroll
      for (int i = 0; i < 4; ++i)
#pragma unroll
        for (int j = 0; j < 4; ++j)
          acc[i][j] += a[i] * b[j];
    }
  }
#pragma unroll
  for (int i = 0; i < 4; ++i) {
    const long row = j0 + tj * 4 + i;
#pragma unroll
    for (int j = 0; j < 4; ++j) {
      const float c = acc[i][j];
      const bf16 h = (bf16)c;
      const long idx = row * 1024 + d0 + td * 4 + j;
      MTh[idx] = h;
      MTl[idx] = (bf16)(c - (float)h);
    }
  }
}

// ---------------------------------------------------------------------------
// value [b][t][d] fp32 -> valueT [b][d][t] bf16
__global__ __launch_bounds__(256) void transpose_convert(
    const float* __restrict__ v, bf16* __restrict__ vT) {
  __shared__ float tile[32][33];
  const int b = blockIdx.z;
  const int t0 = blockIdx.y * 32, d0 = blockIdx.x * 32;
  const int tx = threadIdx.x & 31, ty = threadIdx.x >> 5;
  const float* src = v + (long)b * S * D;
#pragma unroll
  for (int i = 0; i < 4; ++i)
    tile[ty + i * 8][tx] = src[(long)(t0 + ty + i * 8) * D + d0 + tx];
  __syncthreads();
  bf16* dst = vT + (long)b * D * S;
#pragma unroll
  for (int i = 0; i < 4; ++i)
    dst[(long)(d0 + ty + i * 8) * S + t0 + tx] = (bf16)tile[tx][ty + i * 8];
}

// ---------------------------------------------------------------------------
// Split-bf16 GEMM on mfma_f32_32x32x16_bf16 (verbatim R5 structure, 107 us).
// BM=BN=256, BK=32, 512 thr (8 waves 2x4, 128x64/wave = 4x2 frags).
// LDS: 2 bufs x {Ah,Al,Bh,Bl} x 16KB = 128 KB. 3 phases/K-tile (hh, hl, lh):
//   {reads; stage; counted vmcnt; barrier; lgkm(0); setprio 16 MFMA; barrier}
// vmcnt ledger (steady): P1 w6 (retires Bl(t)); P2 w6 (retires Al(t));
// P3 w4 (retires Ah',Bh'). Never drains to 0 mid-loop.
// EPI=0: split-bf16 out + col bias. EPI=1: fp32 out + attn_bias + v1+v2+c.
template <int EPI>
__global__ __launch_bounds__(512, 2) void gemm32_split(
    const bf16* __restrict__ Ah_g, const bf16* __restrict__ Al_g, long a_bs,
    const bf16* __restrict__ Bh_g, const bf16* __restrict__ Bl_g, long b_bs,
    const float* __restrict__ bias,
    bf16* __restrict__ Ch, bf16* __restrict__ Cl,
    float* __restrict__ Cf, long c_bs,
    const float* __restrict__ v1, const float* __restrict__ v2,
    const float* __restrict__ cvec) {
  __shared__ bf16 lds[2 * 4 * ARR];   // 128 KB

  const int tid = threadIdx.x;
  const int lane = tid & 63, wid = tid >> 6;
  const int wr = wid >> 2, wc = wid & 3;          // 2x4 wave grid
  const int lr = lane & 31;                       // row/col within 32-frag
  const int lk = lane >> 5;                       // k-half (0,1)

  // T1 bijective XCD swizzle (nwg=256)
  const int w = blockIdx.x;
  const int swz = (w & 7) * 32 + (w >> 3);
  int z, by, bx;
  if constexpr (EPI == 0) { z = 0; by = swz >> 2; bx = swz & 3; }
  else { z = swz >> 4; by = (swz >> 2) & 3; bx = swz & 3; }
  const long brow = (long)by * GBM, bcol = (long)bx * GBN;

  const bf16* A_h = Ah_g + (long)z * a_bs;
  const bf16* A_l = Al_g + (long)z * a_bs;
  const bf16* B_h = Bh_g + (long)z * b_bs;
  const bf16* B_l = Bl_g + (long)z * b_bs;

  const int srow = tid >> 2;                                  // 0..127
  const int csw = ((tid & 3) ^ ((srow >> 1) & 3)) * 8;        // source pre-swizzle
  const long asrc = (brow + srow) * 1024 + csw;
  const long bsrc = (bcol + srow) * 1024 + csw;
  const int dstoff = wid * 512;                               // wave-uniform base

  // fragment read offsets: row r, k-slice s: chunk = (2s+lk) ^ ((r>>1)&3)
  int aoff[4][2], boff[2][2];
#pragma unroll
  for (int i = 0; i < 4; ++i) {
    const int r = wr * 128 + i * 32 + lr;
#pragma unroll
    for (int s = 0; s < 2; ++s)
      aoff[i][s] = r * 32 + (((2 * s + lk) ^ ((r >> 1) & 3)) * 8);
  }
#pragma unroll
  for (int j = 0; j < 2; ++j) {
    const int r = wc * 64 + j * 32 + lr;
#pragma unroll
    for (int s = 0; s < 2; ++s)
      boff[j][s] = r * 32 + (((2 * s + lk) ^ ((r >> 1) & 3)) * 8);
  }

  f32x16 acc[4][2] = {};
  bf16x8 ah[4][2], al[4][2], bh[2][2], bl[2][2];

#define STG(slot, arr, base, koff, rr) \
  stage16((base) + (koff) + (long)(rr) * 131072, \
          lds + ((slot) * 4 + (arr)) * ARR + (rr) * 4096 + dstoff)

#define CLUSTER(AF, BF) \
  __builtin_amdgcn_s_setprio(1); \
  _Pragma("unroll") \
  for (int s = 0; s < 2; ++s) \
    _Pragma("unroll") \
    for (int i = 0; i < 4; ++i) \
      _Pragma("unroll") \
      for (int j = 0; j < 2; ++j) \
        acc[i][j] = __builtin_amdgcn_mfma_f32_32x32x16_bf16(AF[i][s], BF[j][s], acc[i][j], 0, 0, 0); \
  __builtin_amdgcn_s_setprio(0)

  // ---- prologue: stage tile 0 (order Ah,Bh,Bl,Al); publish Ah,Bh
  STG(0, 0, A_h + asrc, 0, 0); STG(0, 0, A_h + asrc, 0, 1);
  STG(0, 2, B_h + bsrc, 0, 0); STG(0, 2, B_h + bsrc, 0, 1);
  STG(0, 3, B_l + bsrc, 0, 0); STG(0, 3, B_l + bsrc, 0, 1);
  STG(0, 1, A_l + asrc, 0, 0); STG(0, 1, A_l + asrc, 0, 1);
  VMCNT(4);          // Ah0,Bh0 retired; Bl0,Al0 in flight
  SBARRIER;

  for (int t = 0; t < NTK; ++t) {
    const int cur = t & 1, nxt = cur ^ 1;
    const long kn = (long)(t + 1) * GBK;
    const bool pf = (t + 1 < NTK);
    const bf16* lA_h = lds + (cur * 4 + 0) * ARR;
    const bf16* lA_l = lds + (cur * 4 + 1) * ARR;
    const bf16* lB_h = lds + (cur * 4 + 2) * ARR;
    const bf16* lB_l = lds + (cur * 4 + 3) * ARR;

    // ---- P1: read ah,bh | stage Ah',Bh' | vmcnt(6) | bar | lgkm0 | hh
#pragma unroll
    for (int i = 0; i < 4; ++i)
#pragma unroll
      for (int s = 0; s < 2; ++s) ah[i][s] = *(const bf16x8*)&lA_h[aoff[i][s]];
#pragma unroll
    for (int j = 0; j < 2; ++j)
#pragma unroll
      for (int s = 0; s < 2; ++s) bh[j][s] = *(const bf16x8*)&lB_h[boff[j][s]];
    if (pf) {
      STG(nxt, 0, A_h + asrc, kn, 0); STG(nxt, 0, A_h + asrc, kn, 1);
      STG(nxt, 2, B_h + bsrc, kn, 0); STG(nxt, 2, B_h + bsrc, kn, 1);
      VMCNT(6);      // retires Bl(t)
    } else {
      VMCNT(2);      // tail: retires Bl(t), Al(t) still in flight
    }
    SBARRIER; LGKM(0); SB0;
    CLUSTER(ah, bh);
    SBARRIER;

    // ---- P2: read bl | stage Bl' | vmcnt(6) | bar | lgkm0 | hl
#pragma unroll
    for (int j = 0; j < 2; ++j)
#pragma unroll
      for (int s = 0; s < 2; ++s) bl[j][s] = *(const bf16x8*)&lB_l[boff[j][s]];
    if (pf) {
      STG(nxt, 3, B_l + bsrc, kn, 0); STG(nxt, 3, B_l + bsrc, kn, 1);
      VMCNT(6);      // retires Al(t)
    } else {
      VMCNT(0);      // tail: retires Al(t)
    }
    SBARRIER; LGKM(0); SB0;
    CLUSTER(ah, bl);
    SBARRIER;

    // ---- P3: read al | stage Al' | vmcnt(4) | bar | lgkm0 | lh
#pragma unroll
    for (int i = 0; i < 4; ++i)
#pragma unroll
      for (int s = 0; s < 2; ++s) al[i][s] = *(const bf16x8*)&lA_l[aoff[i][s]];
    if (pf) {
      STG(nxt, 1, A_l + asrc, kn, 0); STG(nxt, 1, A_l + asrc, kn, 1);
      VMCNT(4);      // retires Ah',Bh' (visible for P1(t+1))
    }
    SBARRIER; LGKM(0); SB0;
    CLUSTER(al, bh);
    SBARRIER;
  }
#undef STG
#undef CLUSTER

  // Epilogue. 32x32 C/D frag [m74/m101]: col = lane&31,
  // row = (reg&3) + 8*(reg>>2) + 4*(lane>>5)
  if constexpr (EPI == 0) {
#pragma unroll
    for (int j = 0; j < 2; ++j) {
      const long col = bcol + wc * 64 + j * 32 + lr;
      const float bv = bias[col];
#pragma unroll
      for (int i = 0; i < 4; ++i) {
        const long row0 = brow + wr * 128 + i * 32 + 4 * lk;
#pragma unroll
        for (int r = 0; r < 16; ++r) {
          const long row = row0 + (r & 3) + 8 * (r >> 2);
          const float c = acc[i][j][r] + bv;
          const bf16 h = (bf16)c;
          const bf16 l = (bf16)(c - (float)h);
          const long idx = row * 1024 + col;
          Ch[idx] = h;
          Cl[idx] = l;
        }
      }
    }
  } else {
    float* Cz = Cf + (long)z * c_bs;
    const float cc = cvec[0];
    const float* vz1 = v1 + (long)z * 1024;
    const float* vz2 = v2 + (long)z * 1024;
#pragma unroll
    for (int j = 0; j < 2; ++j) {
      const long col = bcol + wc * 64 + j * 32 + lr;
      const float v2c = vz2[col] + cc;
#pragma unroll
      for (int i = 0; i < 4; ++i) {
        const long row0 = brow + wr * 128 + i * 32 + 4 * lk;
#pragma unroll
        for (int r = 0; r < 16; ++r) {
          const long row = row0 + (r & 3) + 8 * (r >> 2);
          Cz[row * 1024 + col] = acc[i][j][r] + bias[row * 1024 + col] + vz1[row] + v2c;
        }
      }
    }
  }
}

// ---------------------------------------------------------------------------
// Plain bf16 GEMM (PV), R3 structure: 2 bufs x {A,B} = 64KB; per K-tile
// stage t+1 ; vmcnt(4) ; barrier ; 12 reads + 32 MFMA ; barrier.
__global__ __launch_bounds__(512, 2) void gemm8_plain(
    const bf16* __restrict__ A_g, long a_bs,
    const bf16* __restrict__ B_g, long b_bs,
    float* __restrict__ C, long c_bs) {
  __shared__ bf16 lds[2 * 2 * ARR];   // 64 KB

  const int tid = threadIdx.x;
  const int lane = tid & 63, wid = tid >> 6;
  const int wr = wid >> 2, wc = wid & 3;
  const int fr = lane & 15, fq = lane >> 4;
  const int fsw = (fr >> 1) & 3;

  const int w = blockIdx.x;
  const int swz = (w & 7) * 32 + (w >> 3);
  const int z = swz >> 4, by = (swz >> 2) & 3, bx = swz & 3;
  const long brow = (long)by * GBM, bcol = (long)bx * GBN;

  const bf16* A = A_g + (long)z * a_bs;
  const bf16* B = B_g + (long)z * b_bs;

  const int srow = tid >> 2;
  const int csw = ((tid & 3) ^ ((srow >> 1) & 3)) * 8;
  const long asrc = (brow + srow) * 1024 + csw;
  const long bsrc = (bcol + srow) * 1024 + csw;
  const int dstoff = wid * 512;

  const int aoffb = (wr * 128 + fr) * 32 + (fq ^ fsw) * 8;
  const int boffb = (wc * 64 + fr) * 32 + (fq ^ fsw) * 8;

  f32x4 acc[8][4] = {};

#define STG2(slot, arr, base, koff, rr) \
  stage16((base) + (koff) + (long)(rr) * 131072, \
          lds + ((slot) * 2 + (arr)) * ARR + (rr) * 4096 + dstoff)

  STG2(0, 0, A + asrc, 0, 0); STG2(0, 0, A + asrc, 0, 1);
  STG2(0, 1, B + bsrc, 0, 0); STG2(0, 1, B + bsrc, 0, 1);

  for (int t = 0; t < NTK; ++t) {
    const int cur = t & 1, nxt = cur ^ 1;
    const bf16* lA = lds + (cur * 2 + 0) * ARR;
    const bf16* lB = lds + (cur * 2 + 1) * ARR;

    if (t + 1 < NTK) {
      const long kn = (long)(t + 1) * GBK;
      STG2(nxt, 0, A + asrc, kn, 0); STG2(nxt, 0, A + asrc, kn, 1);
      STG2(nxt, 1, B + bsrc, kn, 0); STG2(nxt, 1, B + bsrc, kn, 1);
      VMCNT(4);
    } else {
      VMCNT(0);
    }
    SB0;
    SBARRIER;

    bf16x8 ah[8], bh[4];
#pragma unroll
    for (int m = 0; m < 8; ++m) ah[m] = *(const bf16x8*)&lA[aoffb + m * 512];
#pragma unroll
    for (int n = 0; n < 4; ++n) bh[n] = *(const bf16x8*)&lB[boffb + n * 512];
#pragma unroll
    for (int n = 0; n < 4; ++n)
#pragma unroll
      for (int m = 0; m < 8; ++m)
        acc[m][n] = __builtin_amdgcn_mfma_f32_16x16x32_bf16(ah[m], bh[n], acc[m][n], 0, 0, 0);

    SBARRIER;
  }
#undef STG2

  float* Cz = C + (long)z * c_bs;
#pragma unroll
  for (int n = 0; n < 4; ++n) {
    const long col = bcol + wc * 64 + n * 16 + fr;
#pragma unroll
    for (int m = 0; m < 8; ++m) {
      const long row0 = brow + wr * 128 + m * 16 + fq * 4;
#pragma unroll
      for (int j = 0; j < 4; ++j)
        Cz[(row0 + j) * 1024 + col] = acc[m][n][j];
    }
  }
}

// ---------------------------------------------------------------------------
__global__ __launch_bounds__(256) void softmax_rows(
    float* __restrict__ attn, bf16* __restrict__ attn_bf) {
  const long row = blockIdx.x;
  float* p = attn + row * 1024;
  const int tid = threadIdx.x, lane = tid & 63, wid = tid >> 6;

  f32x4 x = ((const f32x4*)p)[tid];
  float m = fmaxf(fmaxf(x[0], x[1]), fmaxf(x[2], x[3]));
#pragma unroll
  for (int off = 32; off; off >>= 1) m = fmaxf(m, __shfl_xor(m, off));
  __shared__ float redm[4];
  if (lane == 0) redm[wid] = m;
  __syncthreads();
  m = fmaxf(fmaxf(redm[0], redm[1]), fmaxf(redm[2], redm[3]));

  f32x4 e;
#pragma unroll
  for (int j = 0; j < 4; ++j) e[j] = __expf(x[j] - m);
  float s = e[0] + e[1] + e[2] + e[3];
#pragma unroll
  for (int off = 32; off; off >>= 1) s += __shfl_xor(s, off);
  __shared__ float reds[4];
  if (lane == 0) reds[wid] = s;
  __syncthreads();
  s = reds[0] + reds[1] + reds[2] + reds[3];

  const float inv = 1.0f / s;
  f32x4 r;
  bf16x4 rb;
#pragma unroll
  for (int j = 0; j < 4; ++j) {
    r[j] = e[j] * inv;
    rb[j] = (bf16)r[j];
  }
  ((f32x4*)p)[tid] = r;
  ((bf16x4*)(attn_bf + row * 1024))[tid] = rb;
}

// ---------------------------------------------------------------------------
extern "C" void kernel_launch(void* const* d_in, const int* in_sizes, int n_in,
                              void* d_out, int out_size, void* d_ws, size_t ws_size,
                              hipStream_t stream) {
  const float* query     = (const float*)d_in[0];
  const float* key       = (const float*)d_in[1];
  const float* value     = (const float*)d_in[2];
  const float* attn_bias = (const float*)d_in[3];
  const float* Wq        = (const float*)d_in[4];
  const float* bq        = (const float*)d_in[5];
  const float* Wk        = (const float*)d_in[6];
  const float* bk        = (const float*)d_in[7];

  float* out  = (float*)d_out;          // [16,1024,1024]
  float* attn = out + NBSD;             // [16,1024,1024]

  // ws carve: 6 big bf16 arrays (192 MiB) + MT splits + fp32 small vectors.
  bf16* ws      = (bf16*)d_ws;
  bf16* k_hi    = ws;                   // split(key)
  bf16* k_lo    = ws + NBSD;
  bf16* qm_hi   = ws + 2 * NBSD;        // split(Q M)
  bf16* qm_lo   = ws + 3 * NBSD;
  bf16* valueT  = ws + 4 * NBSD;
  bf16* attn_bf = ws + 5 * NBSD;
  bf16* smallb  = ws + 6 * NBSD;
  bf16* MT_hi   = smallb;               // [1024,1024]
  bf16* MT_lo   = smallb + 1048576;
  float* fsm    = (float*)(smallb + 2097152);
  float* zeros  = fsm;                  // 1024
  float* w1     = fsm + 1024;           // 1024
  float* w2     = fsm + 2048;           // 1024
  float* cbuf   = fsm + 3072;           // 1
  float* v1     = fsm + 4096;           // 16384
  float* v2     = fsm + 20480;          // 16384
  float* w1p    = fsm + 36864;          // 8x1024
  float* w2p    = fsm + 45056;          // 8x1024
  // query splits live in d_out's attn region (dead once energy writes attn)
  bf16* q_hi = (bf16*)attn;
  bf16* q_lo = q_hi + NBSD;

  // 1) bias-correction precompute: w1 = Wq^T bk, w2 = Wk^T bq, c, zeros
  wpart_kernel<<<65, 256, 0, stream>>>(Wq, Wk, bq, bk, w1p, w2p, cbuf, zeros);
  wreduce_kernel<<<8, 256, 0, stream>>>(w1p, w2p, w1, w2);

  // 2) split conversions with fused rank-1 dots: v1 = query.w1, v2 = key.w2
  split_convert_dot<<<4096, 256, 0, stream>>>(query, q_hi, q_lo, w1, v1);
  split_convert_dot<<<4096, 256, 0, stream>>>(key, k_hi, k_lo, w2, v2);

  // 3) MT = (Wq^T Wk)^T, fp32 outer-product accumulate, split output
  mt_split<<<dim3(16, 16), 256, 0, stream>>>(Wk, Wq, MT_hi, MT_lo);

  // 4) QM = query @ M  (split GEMM, zero col-bias), split output
  gemm32_split<0><<<256, 512, 0, stream>>>(q_hi, q_lo, 0, MT_hi, MT_lo, 0,
                                           zeros, qm_hi, qm_lo, nullptr, 0,
                                           nullptr, nullptr, nullptr);

  // 5) value transpose
  transpose_convert<<<dim3(32, 32, 16), 256, 0, stream>>>(value, valueT);

  // 6) energy = QM K^T + attn_bias + v1[s] + v2[t] + c  (16 z x 4x4 blocks)
  gemm32_split<1><<<256, 512, 0, stream>>>(qm_hi, qm_lo, (long)S * D,
                                           k_hi, k_lo, (long)S * D,
                                           attn_bias, nullptr, nullptr, attn, (long)S * S,
                                           v1, v2, cbuf);

  // 7) softmax in place + bf16 copy
  softmax_rows<<<BATCH * S, 256, 0, stream>>>(attn, attn_bf);

  // 8) out = attention @ value
  gemm8_plain<<<256, 512, 0, stream>>>(attn_bf, (long)S * S, valueT, (long)D * S,
                                       out, (long)S * D);
}